// Round 1
// baseline (354.196 us; speedup 1.0000x reference)
//
#include <hip/hip_runtime.h>
#include <hip/hip_bf16.h>
#include <stdint.h>

// Gate / MoE router: T=524288 rows, D=256, E=64 experts, groups=2x32, topk=4.
// logits = x @ W^T ; softmax ; group containing max logit ; top-4 in group ;
// out = [weights (T*4 f32), indices (T*4 stored as f32 values)].

#define ROWS_PER_BLOCK 256
#define DC 16          // d-elements per staged chunk
#define NCHUNK 16      // 256 / 16
#define LGSTRIDE 68    // logits LDS row stride (17 x 16B, aligned float4)

__device__ __forceinline__ void gload16(const void* g, void* l) {
  __builtin_amdgcn_global_load_lds(
      (const __attribute__((address_space(1))) void*)g,
      (__attribute__((address_space(3))) void*)l, 16, 0, 0);
}

__global__ __launch_bounds__(256) void gate_kernel(
    const float* __restrict__ x, const float* __restrict__ Wt,
    float* __restrict__ out, int T) {
  // LDS layout (floats): XS[2][256][16] @0 (32KB), WS[2][64][16] @8192 (8KB)
  // epilogue union: LG[128][68] @0 (34KB)
  __shared__ float S[10240];  // 40KB

  const int t = threadIdx.x;
  const int lane = t & 63;
  const int w = t >> 6;        // wave id 0..3
  const int li = lane & 7;     // row sub-index
  const int lj = lane >> 3;    // expert group
  const int base_row = blockIdx.x * ROWS_PER_BLOCK;

  float acc[8][8];
#pragma unroll
  for (int a = 0; a < 8; ++a)
#pragma unroll
    for (int b = 0; b < 8; ++b) acc[a][b] = 0.f;

  // Stage chunk c into buffer bi. LDS dest is linear (global_load_lds rule);
  // the XOR bank-swizzle is applied on the GLOBAL source slot instead.
  auto stage = [&](int bi, int c) {
    float* xdst = S + bi * 4096;
#pragma unroll
    for (int q = 0; q < 4; ++q) {
      int L = q * 256 + t;            // 16B slot index in x tile
      int rl = L >> 2;                // block-local row
      int s = L & 3;                  // slot within row (4 x 16B = 64B row)
      const float* src =
          x + (size_t)(base_row + rl) * 256 + c * DC + ((s ^ (rl & 3)) << 2);
      gload16(src, xdst + (size_t)L * 4);
    }
    {
      int e = t >> 2;                 // expert row
      int s = t & 3;
      const float* src =
          Wt + (size_t)e * 256 + c * DC + ((s ^ ((e >> 3) & 3)) << 2);
      float* wdst = S + 8192 + bi * 1024;
      gload16(src, wdst + (size_t)t * 4);
    }
  };

  stage(0, 0);
  __syncthreads();

  for (int c = 0; c < NCHUNK; ++c) {
    if (c + 1 < NCHUNK) stage((c + 1) & 1, c + 1);
    const float* XSb = S + (c & 1) * 4096;
    const float* WSb = S + 8192 + (c & 1) * 1024;
#pragma unroll
    for (int dc = 0; dc < 4; ++dc) {
      float4 xv[8], wv[8];
#pragma unroll
      for (int a = 0; a < 8; ++a)
        xv[a] = *(const float4*)&XSb[(w * 64 + a * 8 + li) * 16 +
                                     ((dc ^ (li & 3)) << 2)];
#pragma unroll
      for (int b = 0; b < 8; ++b)
        wv[b] = *(const float4*)&WSb[(lj * 8 + b) * 16 +
                                     ((dc ^ (lj & 3)) << 2)];
#pragma unroll
      for (int a = 0; a < 8; ++a)
#pragma unroll
        for (int b = 0; b < 8; ++b) {
          acc[a][b] = fmaf(xv[a].x, wv[b].x, acc[a][b]);
          acc[a][b] = fmaf(xv[a].y, wv[b].y, acc[a][b]);
          acc[a][b] = fmaf(xv[a].z, wv[b].z, acc[a][b]);
          acc[a][b] = fmaf(xv[a].w, wv[b].w, acc[a][b]);
        }
    }
    __syncthreads();
  }

  // Epilogue: 2 half-passes of 128 rows through LDS logits buffer.
  for (int p = 0; p < 2; ++p) {
    __syncthreads();
    if ((w >> 1) == p) {
      int r0 = (w & 1) * 64;
#pragma unroll
      for (int a = 0; a < 8; ++a) {
        int rl = r0 + a * 8 + li;
#pragma unroll
        for (int bq = 0; bq < 2; ++bq) {
          float4 v = make_float4(acc[a][bq * 4 + 0], acc[a][bq * 4 + 1],
                                 acc[a][bq * 4 + 2], acc[a][bq * 4 + 3]);
          *(float4*)&S[rl * LGSTRIDE + lj * 8 + bq * 4] = v;
        }
      }
    }
    __syncthreads();
    if (t < 128) {
      const float* Lr = &S[t * LGSTRIDE];
      float l[64];
#pragma unroll
      for (int k = 0; k < 16; ++k)
        *(float4*)&l[k * 4] = *(const float4*)&Lr[k * 4];

      // group maxima (group 0: 0..31, group 1: 32..63)
      float m0 = l[0], m1 = l[32];
#pragma unroll
      for (int k = 1; k < 32; ++k) {
        m0 = fmaxf(m0, l[k]);
        m1 = fmaxf(m1, l[32 + k]);
      }
      float m = fmaxf(m0, m1);
      int g = (m1 > m0) ? 1 : 0;  // tie -> group 0 (top_k lower-index-first)

      // softmax denominator over ALL 64 experts
      float sum = 0.f;
#pragma unroll
      for (int k = 0; k < 64; ++k) sum += __expf(l[k] - m);
      float inv = 1.0f / sum;

      // top-4 within the selected group (strict > keeps lowest index on ties)
      float lv[32];
#pragma unroll
      for (int k = 0; k < 32; ++k) lv[k] = g ? l[32 + k] : l[k];

      float wv4[4];
      int iv4[4];
#pragma unroll
      for (int pp = 0; pp < 4; ++pp) {
        float best = lv[0];
        int bsel = 0;
#pragma unroll
        for (int k = 1; k < 32; ++k) {
          bool cnd = lv[k] > best;
          best = cnd ? lv[k] : best;
          bsel = cnd ? k : bsel;
        }
        wv4[pp] = __expf(best - m) * inv;
        iv4[pp] = g * 32 + bsel;
#pragma unroll
        for (int k = 0; k < 32; ++k)
          lv[k] = (k == bsel) ? -__builtin_inff() : lv[k];
      }

      size_t rg = (size_t)base_row + (size_t)p * 128 + t;
      *(float4*)&out[rg * 4] = make_float4(wv4[0], wv4[1], wv4[2], wv4[3]);
      *(float4*)&out[(size_t)T * 4 + rg * 4] =
          make_float4((float)iv4[0], (float)iv4[1], (float)iv4[2],
                      (float)iv4[3]);
    }
  }
}

extern "C" void kernel_launch(void* const* d_in, const int* in_sizes, int n_in,
                              void* d_out, int out_size, void* d_ws,
                              size_t ws_size, hipStream_t stream) {
  const float* x = (const float*)d_in[0];
  const float* Wt = (const float*)d_in[1];
  float* out = (float*)d_out;
  int T = in_sizes[0] / 256;               // D = 256
  int grid = T / ROWS_PER_BLOCK;           // T = 524288 -> 2048 blocks
  hipLaunchKernelGGL(gate_kernel, dim3(grid), dim3(256), 0, stream, x, Wt, out,
                     T);
}